// Round 2
// baseline (181.540 us; speedup 1.0000x reference)
//
#include <hip/hip_runtime.h>
#include <stdint.h>

#define B_  2
#define S_  2048
#define D_  1024
#define H_  16
#define HD_ 64
#define M_  (B_*S_)   // 4096 rows

typedef __bf16 bf16x8 __attribute__((ext_vector_type(8)));
typedef float  f32x4  __attribute__((ext_vector_type(4)));

typedef const __attribute__((address_space(1))) void* gas_ptr;
typedef __attribute__((address_space(3))) void* las_ptr;

__device__ __forceinline__ uint16_t f32_to_bf16(float f) {
  uint32_t u = __float_as_uint(f);
  u += 0x7FFFu + ((u >> 16) & 1u);   // RNE; inputs are finite
  return (uint16_t)(u >> 16);
}

// RTZ: 1 VALU op; used only for P (positive, bias cancels in num/den)
__device__ __forceinline__ uint16_t f32_to_bf16_rtz(float f) {
  return (uint16_t)(__float_as_uint(f) >> 16);
}

__device__ __forceinline__ void g2l16(const uint16_t* g, uint16_t* l) {
  // async global->LDS: per-lane global addr; LDS dest = wave-uniform base + lane*16
  __builtin_amdgcn_global_load_lds((gas_ptr)g, (las_ptr)l, 16, 0, 0);
}

// Bank swizzle: chunk c of row r stored at slot 4r + (c ^ ((r>>1)&3)).
// Fill side: slot s sources global (row s>>2, chunk (s&3)^((s>>3)&3)).
// Read side: row base%16==0 + l16, chunk q -> q ^ ((l16>>1)&3). 2-way banks (free).
__device__ __forceinline__ int swz_src(int s) {   // uint16 offset in row-major panel
  return (s >> 2) * D_ + (((s & 3) ^ ((s >> 3) & 3)) * 8);
}

// one launch for all 5 fp32->bf16 casts (x + 4 weights); all sizes are pow2
__global__ void cast_all(const float* __restrict__ x,
                         const float* __restrict__ wq, const float* __restrict__ wk,
                         const float* __restrict__ wv, const float* __restrict__ wf,
                         uint16_t* __restrict__ xb,
                         uint16_t* __restrict__ wqb, uint16_t* __restrict__ wkb,
                         uint16_t* __restrict__ wvb, uint16_t* __restrict__ wfb) {
  const int X4 = M_ * D_ / 4;        // 1M float4
  const int W4 = D_ * D_ / 4;        // 256K float4
  int i = blockIdx.x * 256 + threadIdx.x;
  const float* src; uint16_t* dst; int off;
  if (i < X4) { src = x; dst = xb; off = i; }
  else {
    int j = i - X4;
    int w = j >> 18;                 // / W4
    off = j & (W4 - 1);
    src = (w == 0) ? wq : (w == 1) ? wk : (w == 2) ? wv : wf;
    dst = (w == 0) ? wqb : (w == 1) ? wkb : (w == 2) ? wvb : wfb;
  }
  float4 v = ((const float4*)src)[off];
  ushort4 o;
  o.x = f32_to_bf16(v.x); o.y = f32_to_bf16(v.y);
  o.z = f32_to_bf16(v.z); o.w = f32_to_bf16(v.w);
  ((ushort4*)dst)[off] = o;
}

// qkv_gemm v3: 256x256 tile, BK=64, 8 waves (2Mx4N). K-tile split by k-half:
// phases {0,1} consume khalf0, {2,3} consume khalf1. Prefetch t+1 khalf-h is
// issued at phase 2h; COUNTED waits only: vmcnt(8) at p1-end (current tile's
// h1 ready, ~4 phases of cover), vmcnt(4) at p3-end (next tile's h0 ready,
// ~3 phases). vmcnt never drains to 0 in steady state (T4, m218 +38%).
// 2 barriers/phase + lgkmcnt(0) + setprio(1) around each 16-MFMA cluster.
// Q,K -> [B,H,S,HD]; V -> transposed [B,H,HD,S]. Q pre-scaled 0.125*log2(e).
__global__ __launch_bounds__(512, 2)
void qkv_gemm(const uint16_t* __restrict__ xb,
              const uint16_t* __restrict__ wqb, const uint16_t* __restrict__ wkb,
              const uint16_t* __restrict__ wvb,
              const float* __restrict__ bqv, const float* __restrict__ bkv,
              const float* __restrict__ bvv,
              uint16_t* __restrict__ qout, uint16_t* __restrict__ kout,
              uint16_t* __restrict__ vtout)
{
  // [buf][khalf][1024 slots * 8]: 64KB each => 128KB total, 1 block/CU
  __shared__ __align__(16) uint16_t As[2][2][8192];
  __shared__ __align__(16) uint16_t Bs[2][2][8192];

  const int wsel = blockIdx.x >> 2;          // 0=Q 1=K 2=V
  const int nsel = blockIdx.x & 3;
  const int mtile = blockIdx.y;
  const int tid  = threadIdx.x;
  const int lane = tid & 63, wave = tid >> 6;
  const int quad = lane >> 4, l16 = lane & 15;
  const int wm = (wave >> 2) * 128;          // wave row offset in 256
  const int wn = (wave & 3) * 64;            // wave col offset in 256
  const int sw = quad ^ ((l16 >> 1) & 3);

  const uint16_t *Ap, *Bp;
  int m0e, n0e;
  if (wsel < 2) {
    Ap = xb; Bp = (wsel == 0) ? wqb : wkb;
    m0e = mtile * 256; n0e = nsel * 256;
  } else {
    Ap = wvb; Bp = xb;
    m0e = nsel * 256; n0e = mtile * 256;
  }

  // staging: each half-panel (256 rows x 32 cols = 1024 slots) filled by 512
  // threads in 2 issues; slot s = i*512 + tid; wave-uniform LDS base.
  const int so0 = swz_src(tid);
  const int so1 = swz_src(tid + 512);
  const uint16_t* gA = Ap + (size_t)m0e * D_;
  const uint16_t* gB = Bp + (size_t)n0e * D_;
  const int d0 = (wave * 64) * 8;            // issue 0 dest (uint16 units)
  const int d1 = (512 + wave * 64) * 8;      // issue 1 dest

  f32x4 acc[8][4];
  #pragma unroll
  for (int i = 0; i < 8; ++i)
    #pragma unroll
    for (int j = 0; j < 4; ++j)
      #pragma unroll
      for (int e = 0; e < 4; ++e)
        acc[i][j][e] = 0.f;

  // prologue: stage tile 0 (h0 group of 4 first, then h1 group of 4),
  // wait only for h0 before entering phase 0.
  g2l16(gA + so0,      &As[0][0][d0]);
  g2l16(gA + so1,      &As[0][0][d1]);
  g2l16(gB + so0,      &Bs[0][0][d0]);
  g2l16(gB + so1,      &Bs[0][0][d1]);
  g2l16(gA + 32 + so0, &As[0][1][d0]);
  g2l16(gA + 32 + so1, &As[0][1][d1]);
  g2l16(gB + 32 + so0, &Bs[0][1][d0]);
  g2l16(gB + 32 + so1, &Bs[0][1][d1]);
  asm volatile("s_waitcnt vmcnt(4)" ::: "memory");
  __builtin_amdgcn_s_barrier();

  bf16x8 bfr[4], afr[4];
  for (int t = 0; t < 16; ++t) {
    const int c = t & 1, cn = c ^ 1;
    const bool pf = (t < 15);
    const int kn = (t + 1) * 64;
    #pragma unroll
    for (int h = 0; h < 2; ++h) {
      // ---- phase 2h: bfr[h] (4 reads) + afr mt0-3 (4 reads); issue t+1.h ----
      #pragma unroll
      for (int nt = 0; nt < 4; ++nt) {
        const int ro = ((wn + nt * 16 + l16) * 4 + sw) * 8;
        bfr[nt] = *(const bf16x8*)(&Bs[c][h][ro]);
      }
      #pragma unroll
      for (int i = 0; i < 4; ++i) {
        const int ro = ((wm + i * 16 + l16) * 4 + sw) * 8;
        afr[i] = *(const bf16x8*)(&As[c][h][ro]);
      }
      if (pf) {
        g2l16(gA + kn + h * 32 + so0, &As[cn][h][d0]);
        g2l16(gA + kn + h * 32 + so1, &As[cn][h][d1]);
        g2l16(gB + kn + h * 32 + so0, &Bs[cn][h][d0]);
        g2l16(gB + kn + h * 32 + so1, &Bs[cn][h][d1]);
      }
      __builtin_amdgcn_s_barrier();
      asm volatile("s_waitcnt lgkmcnt(0)" ::: "memory");
      __builtin_amdgcn_sched_barrier(0);
      __builtin_amdgcn_s_setprio(1);
      #pragma unroll
      for (int i = 0; i < 4; ++i)
        #pragma unroll
        for (int nt = 0; nt < 4; ++nt)
          acc[i][nt] = __builtin_amdgcn_mfma_f32_16x16x32_bf16(
              afr[i], bfr[nt], acc[i][nt], 0, 0, 0);
      __builtin_amdgcn_s_setprio(0);
      __builtin_amdgcn_s_barrier();

      // ---- phase 2h+1: afr mt4-7 (4 reads) ----
      #pragma unroll
      for (int i = 0; i < 4; ++i) {
        const int ro = ((wm + (4 + i) * 16 + l16) * 4 + sw) * 8;
        afr[i] = *(const bf16x8*)(&As[c][h][ro]);
      }
      __builtin_amdgcn_s_barrier();
      asm volatile("s_waitcnt lgkmcnt(0)" ::: "memory");
      __builtin_amdgcn_sched_barrier(0);
      __builtin_amdgcn_s_setprio(1);
      #pragma unroll
      for (int i = 0; i < 4; ++i)
        #pragma unroll
        for (int nt = 0; nt < 4; ++nt)
          acc[4 + i][nt] = __builtin_amdgcn_mfma_f32_16x16x32_bf16(
              afr[i], bfr[nt], acc[4 + i][nt], 0, 0, 0);
      __builtin_amdgcn_s_setprio(0);
      if (h == 0) {
        // need current tile's h1 in LDS before phase 2 reads it.
        // outstanding (oldest first): t.h1(4), t+1.h0(4), t+1.h1(4)
        if (pf) asm volatile("s_waitcnt vmcnt(8)" ::: "memory");
        else    asm volatile("s_waitcnt vmcnt(0)" ::: "memory");
      } else {
        // need next tile's h0 before its phase 0; leaves t+1.h1 in flight
        asm volatile("s_waitcnt vmcnt(4)" ::: "memory");
      }
      __builtin_amdgcn_s_barrier();
    }
  }

  if (wsel < 2) {
    const float* bias = (wsel == 0) ? bqv : bkv;
    uint16_t* outp = (wsel == 0) ? qout : kout;
    const float scl = (wsel == 0) ? 0.18033688f : 1.0f;
    #pragma unroll
    for (int nt = 0; nt < 4; ++nt) {
      const int n = n0e + wn + nt * 16 + l16;
      const int h = n >> 6, hd = n & 63;
      const float bia = bias[n];
      #pragma unroll
      for (int mt = 0; mt < 8; ++mt) {
        #pragma unroll
        for (int r = 0; r < 4; ++r) {
          const int m = m0e + wm + mt * 16 + quad * 4 + r;
          const int bb = m >> 11, s = m & (S_ - 1);
          outp[(((size_t)(bb * H_ + h)) * S_ + s) * HD_ + hd] =
              f32_to_bf16((acc[mt][nt][r] + bia) * scl);
        }
      }
    }
  } else {
    #pragma unroll
    for (int mt = 0; mt < 8; ++mt) {
      #pragma unroll
      for (int r = 0; r < 4; ++r) {
        const int m = m0e + wm + mt * 16 + quad * 4 + r;
        const int h = m >> 6, hd = m & 63;
        const float bia = bvv[m];
        #pragma unroll
        for (int nt = 0; nt < 4; ++nt) {
          const int n = n0e + wn + nt * 16 + l16;
          const int bb = n >> 11, s = n & (S_ - 1);
          vtout[(((size_t)(bb * H_ + h)) * HD_ + hd) * S_ + s] =
              f32_to_bf16(acc[mt][nt][r] + bia);
        }
      }
    }
  }
}

// flash v6: double-buffered K/V across key-tiles (T14 issue-early/write-late
// analog): issue tile t+1's 4 g2l16 BEFORE computing tile t, __syncthreads
// after compute -- the full QK/softmax/PV chain covers the load latency
// (R1 counters: MfmaUtil 14.6, nothing saturated = exposed latency every
// tile from issue->sync->compute ordering). setprio(1) around both MFMA
// clusters (T5, m191). LDS 41.2KB -> 3 blocks/CU.
__global__ __launch_bounds__(256)
void flash_attn(const uint16_t* __restrict__ qb, const uint16_t* __restrict__ kb,
                const uint16_t* __restrict__ vtb, uint16_t* __restrict__ ao)
{
  __shared__ __align__(16) uint16_t ks[2][2][2048];   // [buf][chunk c][64r x 32c]
  __shared__ __align__(16) uint16_t vs[2][2][2048];   // [buf][chunk c][64hd x 32k]
  __shared__ __align__(16) uint16_t p_lds[4][16][72]; // P transpose, wave-private

  const int bh = blockIdx.x;
  const int qt = (int)(gridDim.y - 1u - blockIdx.y);  // heavy blocks first
  const int wave = threadIdx.x >> 6, lane = threadIdx.x & 63;
  const int quad = lane >> 4, l16 = lane & 15;
  const int sw = quad ^ ((l16 >> 1) & 3);
  const int q0 = qt * 64;

  const uint16_t* Q  = qb  + (size_t)bh * S_ * HD_;
  const uint16_t* Kp = kb  + (size_t)bh * S_ * HD_;
  const uint16_t* Vt = vtb + (size_t)bh * HD_ * S_;

  // Q fragments for this wave's 16 rows: A[m=l16][k=quad*8+j]
  const int qrow = q0 + wave * 16;
  bf16x8 aq0 = *(const bf16x8*)(Q + (size_t)(qrow + l16) * HD_ + quad * 8);
  bf16x8 aq1 = *(const bf16x8*)(Q + (size_t)(qrow + l16) * HD_ + 32 + quad * 8);

  // staging: 16 x 1KB groups per tile; wave w handles groups 4w..4w+3.
  // groups 0-7: K (chunk g>>2, rowblk g&3); 8-15: V^T likewise. Swizzled fill.
  const int srow = lane >> 2;                       // local row 0..15
  const int schk = (lane & 3) ^ ((lane >> 3) & 3);  // swizzled source chunk
  const uint16_t* sb[4]; uint16_t* sd0[4]; uint16_t* sd1[4]; int sstep[4];
  #pragma unroll
  for (int j = 0; j < 4; ++j) {
    const int g = wave * 4 + j;
    if (g < 8) {
      const int c = (g >> 2) & 1, rb = g & 3;
      sd0[j] = &ks[0][c][rb * 512];
      sd1[j] = &ks[1][c][rb * 512];
      sb[j] = Kp + (size_t)(rb * 16 + srow) * HD_ + c * 32 + schk * 8;
      sstep[j] = 64 * HD_;          // advance 64 key-rows per tile
    } else {
      const int gg = g - 8, c = (gg >> 2) & 1, rb = gg & 3;
      sd0[j] = &vs[0][c][rb * 512];
      sd1[j] = &vs[1][c][rb * 512];
      sb[j] = Vt + (size_t)(rb * 16 + srow) * S_ + c * 32 + schk * 8;
      sstep[j] = 64;                // advance 64 key-cols per tile
    }
  }

  float lpart[4];
  f32x4 o[4];
  #pragma unroll
  for (int r = 0; r < 4; ++r) lpart[r] = 0.f;
  #pragma unroll
  for (int t = 0; t < 4; ++t)
    #pragma unroll
    for (int e = 0; e < 4; ++e) o[t][e] = 0.f;

  const int rowid = qrow + quad * 4;    // +r = this lane's score rows

  // prologue: stage tile 0 into buf 0
  #pragma unroll
  for (int j = 0; j < 4; ++j) {
    g2l16(sb[j], sd0[j]);
    sb[j] += sstep[j];
  }
  __syncthreads();

  for (int kt = 0; kt <= qt; ++kt) {
    const int kbase = kt * 64;
    const bool diag = (kt == qt);
    const int cb = kt & 1;

    // prefetch tile kt+1 into the other buffer; latency hides under compute
    if (kt < qt) {
      #pragma unroll
      for (int j = 0; j < 4; ++j) {
        g2l16(sb[j], cb ? sd0[j] : sd1[j]);
        sb[j] += sstep[j];
      }
    }

    bf16x8 kf0[4], kf1[4];
    #pragma unroll
    for (int nt = 0; nt < 4; ++nt) {
      kf0[nt] = *(const bf16x8*)(&ks[cb][0][((nt * 16 + l16) * 4 + sw) * 8]);
      kf1[nt] = *(const bf16x8*)(&ks[cb][1][((nt * 16 + l16) * 4 + sw) * 8]);
    }
    f32x4 sacc[4];
    __builtin_amdgcn_s_setprio(1);
    #pragma unroll
    for (int nt = 0; nt < 4; ++nt) {
      #pragma unroll
      for (int e = 0; e < 4; ++e) sacc[nt][e] = 0.f;
      sacc[nt] = __builtin_amdgcn_mfma_f32_16x16x32_bf16(aq0, kf0[nt], sacc[nt], 0, 0, 0);
      sacc[nt] = __builtin_amdgcn_mfma_f32_16x16x32_bf16(aq1, kf1[nt], sacc[nt], 0, 0, 0);
    }
    __builtin_amdgcn_s_setprio(0);

    bf16x8 vf0[4], vf1[4];
    #pragma unroll
    for (int t = 0; t < 4; ++t) {
      vf0[t] = *(const bf16x8*)(&vs[cb][0][((t * 16 + l16) * 4 + sw) * 8]);
      vf1[t] = *(const bf16x8*)(&vs[cb][1][((t * 16 + l16) * 4 + sw) * 8]);
    }

    // max-free softmax: p = exp2(s) (log2e folded into Q); masked -> 0; RTZ
    #pragma unroll
    for (int nt = 0; nt < 4; ++nt) {
      const int kkc = kbase + nt * 16 + l16;
      #pragma unroll
      for (int r = 0; r < 4; ++r) {
        float p = __builtin_amdgcn_exp2f(sacc[nt][r]);
        if (diag && (kkc > rowid + r)) p = 0.f;
        lpart[r] += p;
        p_lds[wave][quad * 4 + r][nt * 16 + l16] = f32_to_bf16_rtz(p);
      }
    }

    // P: C-layout -> A-layout via wave-private LDS (DS ops in-order per wave)
    bf16x8 ap0 = *(const bf16x8*)(&p_lds[wave][l16][quad * 8]);
    bf16x8 ap1 = *(const bf16x8*)(&p_lds[wave][l16][32 + quad * 8]);
    __builtin_amdgcn_s_setprio(1);
    #pragma unroll
    for (int t = 0; t < 4; ++t) {      // O += P V
      o[t] = __builtin_amdgcn_mfma_f32_16x16x32_bf16(ap0, vf0[t], o[t], 0, 0, 0);
      o[t] = __builtin_amdgcn_mfma_f32_16x16x32_bf16(ap1, vf1[t], o[t], 0, 0, 0);
    }
    __builtin_amdgcn_s_setprio(0);
    __syncthreads();    // prefetch landed + all waves done reading buf cb
  }

  // wave-complete rows: butterfly row-sum, then store
  #pragma unroll
  for (int r = 0; r < 4; ++r) {
    lpart[r] += __shfl_xor(lpart[r], 1, 64);
    lpart[r] += __shfl_xor(lpart[r], 2, 64);
    lpart[r] += __shfl_xor(lpart[r], 4, 64);
    lpart[r] += __shfl_xor(lpart[r], 8, 64);
  }
  const int bb = bh >> 4, h = bh & 15;
  #pragma unroll
  for (int t = 0; t < 4; ++t) {
    #pragma unroll
    for (int r = 0; r < 4; ++r) {
      const float ov = o[t][r] / lpart[r];
      ao[((size_t)(bb * S_ + rowid + r)) * D_ + h * HD_ + t * 16 + l16] =
          f32_to_bf16(ov);
    }
  }
}

// out_gemm v2: 64x128 tile with BK=64 (same barrier-halving as qkv R10).
// Per iter: 6 g2l16, 12 ds_read_b128, 16 MFMA/wave, 2 barriers; 16 iters.
// LDS 24KB -> 6 blocks/CU; 512 blocks = 2/CU grid.
__global__ __launch_bounds__(256)
void out_gemm(const uint16_t* __restrict__ ab, const uint16_t* __restrict__ wfb,
              const float* __restrict__ bfv, float* __restrict__ out)
{
  __shared__ __align__(16) uint16_t As[2 * 64 * 32];
  __shared__ __align__(16) uint16_t Bs[2 * 128 * 32];
  const int m0 = blockIdx.y * 64;            // y = m-tile (XCD: id mod 8 = x)
  const int n0 = blockIdx.x * 128;           // x = weight N-tile
  const int lane = threadIdx.x & 63, wave = threadIdx.x >> 6;
  const int quad = lane >> 4, l16 = lane & 15;
  const int wm = (wave >> 1) * 32, wn = (wave & 1) * 64;
  const int sw = quad ^ ((l16 >> 1) & 3);

  f32x4 acc[2][4];
  #pragma unroll
  for (int i = 0; i < 2; ++i)
    #pragma unroll
    for (int j = 0; j < 4; ++j)
      #pragma unroll
      for (int e = 0; e < 4; ++e)
        acc[i][j][e] = 0.f;

  const int sA  = wave * 64 + lane;          // A: 64 rows = 256 slots/panel
  const int sB1 = sA + 256;                  // B: 128 rows = 512 slots/panel
  const int soA = swz_src(sA), soB1 = swz_src(sB1);
  uint16_t* lA  = As + (size_t)(wave * 64) * 8;
  uint16_t* lB0 = Bs + (size_t)(wave * 64) * 8;
  uint16_t* lB1 = Bs + (size_t)(256 + wave * 64) * 8;
  const uint16_t* gA  = ab  + (size_t)m0 * D_ + soA;
  const uint16_t* gB0 = wfb + (size_t)n0 * D_ + soA;
  const uint16_t* gB1 = wfb + (size_t)n0 * D_ + soB1;

  for (int k0 = 0; k0 < D_; k0 += 64) {
    g2l16(gA  + k0,      lA);
    g2l16(gB0 + k0,      lB0);
    g2l16(gB1 + k0,      lB1);
    g2l16(gA  + k0 + 32, lA  + 2048);   // A panel 1 at +64*32
    g2l16(gB0 + k0 + 32, lB0 + 4096);   // B panel 1 at +128*32
    g2l16(gB1 + k0 + 32, lB1 + 4096);
    __syncthreads();
    bf16x8 af0[2], af1[2], bf0[4], bf1[4];
    #pragma unroll
    for (int mt = 0; mt < 2; ++mt) {
      const int ro = ((wm + mt * 16 + l16) * 4 + sw) * 8;
      af0[mt] = *(const bf16x8*)(As + ro);
      af1[mt] = *(const bf16x8*)(As + 2048 + ro);
    }
    #pragma unroll
    for (int nt = 0; nt < 4; ++nt) {
      const int ro = ((wn + nt * 16 + l16) * 4 + sw) * 8;
      bf0[nt] = *(const bf16x8*)(Bs + ro);
      bf1[nt] = *(const bf16x8*)(Bs + 4096 + ro);
    }
    #pragma unroll
    for (int mt = 0; mt < 2; ++mt)
      #pragma unroll
      for (int nt = 0; nt < 4; ++nt) {
        acc[mt][nt] = __builtin_amdgcn_mfma_f32_16x16x32_bf16(
            af0[mt], bf0[nt], acc[mt][nt], 0, 0, 0);
        acc[mt][nt] = __builtin_amdgcn_mfma_f32_16x16x32_bf16(
            af1[mt], bf1[nt], acc[mt][nt], 0, 0, 0);
      }
    __syncthreads();
  }

  #pragma unroll
  for (int nt = 0; nt < 4; ++nt) {
    const int n = n0 + wn + nt * 16 + l16;
    const float bia = bfv[n];
    #pragma unroll
    for (int mt = 0; mt < 2; ++mt) {
      #pragma unroll
      for (int r = 0; r < 4; ++r) {
        const int m = m0 + wm + mt * 16 + quad * 4 + r;
        out[(size_t)m * D_ + n] = acc[mt][nt][r] + bia;
      }
    }
  }
}

extern "C" void kernel_launch(void* const* d_in, const int* in_sizes, int n_in,
                              void* d_out, int out_size, void* d_ws, size_t ws_size,
                              hipStream_t stream) {
  (void)in_sizes; (void)n_in; (void)out_size; (void)ws_size;
  const float* x  = (const float*)d_in[0];
  const float* Wq = (const float*)d_in[1];
  const float* bq = (const float*)d_in[2];
  const float* Wk = (const float*)d_in[3];
  const float* bk = (const float*)d_in[4];
  const float* Wv = (const float*)d_in[5];
  const float* bv = (const float*)d_in[6];
  const float* Wf = (const float*)d_in[7];
  const float* bf = (const float*)d_in[8];
  float* out = (float*)d_out;

  uint16_t* ws = (uint16_t*)d_ws;
  uint16_t* xb   = ws;
  uint16_t* wqb  = xb  + (size_t)M_ * D_;
  uint16_t* wkb  = wqb + (size_t)D_ * D_;
  uint16_t* wvb  = wkb + (size_t)D_ * D_;
  uint16_t* wfb  = wvb + (size_t)D_ * D_;
  uint16_t* qbuf = wfb + (size_t)D_ * D_;
  uint16_t* kbuf = qbuf + (size_t)M_ * D_;
  uint16_t* vtb  = kbuf + (size_t)M_ * D_;
  uint16_t* aob  = vtb  + (size_t)M_ * D_;

  const int CAST_BLOCKS = (M_ * D_ / 4 + 4 * (D_ * D_ / 4)) / 256;   // 8192
  cast_all<<<CAST_BLOCKS, 256, 0, stream>>>(x, Wq, Wk, Wv, Wf,
                                            xb, wqb, wkb, wvb, wfb);

  qkv_gemm<<<dim3(12, 16), 512, 0, stream>>>(xb, wqb, wkb, wvb, bq, bk, bv,
                                             qbuf, kbuf, vtb);
  flash_attn<<<dim3(32, 32), 256, 0, stream>>>(qbuf, kbuf, vtb, aob);
  out_gemm<<<dim3(8, 64), 256, 0, stream>>>(aob, wfb, bf, out);
}

// Round 3
// 179.000 us; speedup vs baseline: 1.0142x; 1.0142x over previous
//
#include <hip/hip_runtime.h>
#include <stdint.h>

#define B_  2
#define S_  2048
#define D_  1024
#define H_  16
#define HD_ 64
#define M_  (B_*S_)   // 4096 rows

typedef __bf16 bf16x8 __attribute__((ext_vector_type(8)));
typedef float  f32x4  __attribute__((ext_vector_type(4)));

typedef const __attribute__((address_space(1))) void* gas_ptr;
typedef __attribute__((address_space(3))) void* las_ptr;

__device__ __forceinline__ uint16_t f32_to_bf16(float f) {
  uint32_t u = __float_as_uint(f);
  u += 0x7FFFu + ((u >> 16) & 1u);   // RNE; inputs are finite
  return (uint16_t)(u >> 16);
}

// RTZ: 1 VALU op; used only for P (positive, bias cancels in num/den)
__device__ __forceinline__ uint16_t f32_to_bf16_rtz(float f) {
  return (uint16_t)(__float_as_uint(f) >> 16);
}

__device__ __forceinline__ void g2l16(const uint16_t* g, uint16_t* l) {
  // async global->LDS: per-lane global addr; LDS dest = wave-uniform base + lane*16
  __builtin_amdgcn_global_load_lds((gas_ptr)g, (las_ptr)l, 16, 0, 0);
}

// Bank swizzle: chunk c of row r stored at slot 4r + (c ^ ((r>>1)&3)).
// Fill side: slot s sources global (row s>>2, chunk (s&3)^((s>>3)&3)).
// Read side: row base%16==0 + l16, chunk q -> q ^ ((l16>>1)&3). 2-way banks (free).
__device__ __forceinline__ int swz_src(int s) {   // uint16 offset in row-major panel
  return (s >> 2) * D_ + (((s & 3) ^ ((s >> 3) & 3)) * 8);
}

// one launch for all 5 fp32->bf16 casts (x + 4 weights); all sizes are pow2
__global__ void cast_all(const float* __restrict__ x,
                         const float* __restrict__ wq, const float* __restrict__ wk,
                         const float* __restrict__ wv, const float* __restrict__ wf,
                         uint16_t* __restrict__ xb,
                         uint16_t* __restrict__ wqb, uint16_t* __restrict__ wkb,
                         uint16_t* __restrict__ wvb, uint16_t* __restrict__ wfb) {
  const int X4 = M_ * D_ / 4;        // 1M float4
  const int W4 = D_ * D_ / 4;        // 256K float4
  int i = blockIdx.x * 256 + threadIdx.x;
  const float* src; uint16_t* dst; int off;
  if (i < X4) { src = x; dst = xb; off = i; }
  else {
    int j = i - X4;
    int w = j >> 18;                 // / W4
    off = j & (W4 - 1);
    src = (w == 0) ? wq : (w == 1) ? wk : (w == 2) ? wv : wf;
    dst = (w == 0) ? wqb : (w == 1) ? wkb : (w == 2) ? wvb : wfb;
  }
  float4 v = ((const float4*)src)[off];
  ushort4 o;
  o.x = f32_to_bf16(v.x); o.y = f32_to_bf16(v.y);
  o.z = f32_to_bf16(v.z); o.w = f32_to_bf16(v.w);
  ((ushort4*)dst)[off] = o;
}

// qkv_gemm v4: 256x256, BK=64, 8 waves (2Mx4N). Key change vs v2/v3 (both
// null): reads and MFMAs are INTERLEAVED in each wave's stream instead of
// section-separated by barriers. Per K-tile: ONE barrier, 4 pipeline steps;
// each step issues the NEXT group's ds_reads (4-8), then waits COUNTED
// lgkmcnt leaving them outstanding, then runs 16 MFMA -- LDS pipe and MFMA
// pipe busy simultaneously. All 8 g2l prefetches issue at step 1; vmcnt(0)
// sits ~3 MFMA sections (~1800cy) later. Groups: R1(h)=bfr, R2(h)=af03,
// R3(h)=af47; M1(h)=acc[0..3], M2(h)=acc[4..7].
__global__ __launch_bounds__(512, 2)
void qkv_gemm(const uint16_t* __restrict__ xb,
              const uint16_t* __restrict__ wqb, const uint16_t* __restrict__ wkb,
              const uint16_t* __restrict__ wvb,
              const float* __restrict__ bqv, const float* __restrict__ bkv,
              const float* __restrict__ bvv,
              uint16_t* __restrict__ qout, uint16_t* __restrict__ kout,
              uint16_t* __restrict__ vtout)
{
  // [buf][khalf][1024 slots * 8]: 128KB total, 1 block/CU
  __shared__ __align__(16) uint16_t As[2][2][8192];
  __shared__ __align__(16) uint16_t Bs[2][2][8192];

  const int wsel = blockIdx.x >> 2;          // 0=Q 1=K 2=V
  const int nsel = blockIdx.x & 3;
  const int mtile = blockIdx.y;
  const int tid  = threadIdx.x;
  const int lane = tid & 63, wave = tid >> 6;
  const int quad = lane >> 4, l16 = lane & 15;
  const int wm = (wave >> 2) * 128;          // wave row offset in 256
  const int wn = (wave & 3) * 64;            // wave col offset in 256
  const int sw = quad ^ ((l16 >> 1) & 3);

  const uint16_t *Ap, *Bp;
  int m0e, n0e;
  if (wsel < 2) {
    Ap = xb; Bp = (wsel == 0) ? wqb : wkb;
    m0e = mtile * 256; n0e = nsel * 256;
  } else {
    Ap = wvb; Bp = xb;
    m0e = nsel * 256; n0e = mtile * 256;
  }

  const int so0 = swz_src(tid);
  const int so1 = swz_src(tid + 512);
  const uint16_t* gA = Ap + (size_t)m0e * D_;
  const uint16_t* gB = Bp + (size_t)n0e * D_;
  const int d0 = (wave * 64) * 8;            // issue 0 dest (uint16 units)
  const int d1 = (512 + wave * 64) * 8;      // issue 1 dest

  f32x4 acc[8][4];
  #pragma unroll
  for (int i = 0; i < 8; ++i)
    #pragma unroll
    for (int j = 0; j < 4; ++j)
      #pragma unroll
      for (int e = 0; e < 4; ++e)
        acc[i][j][e] = 0.f;

  // prologue: stage tile 0 into buf 0, drain, then issue R1(0),R2(0)
  #pragma unroll
  for (int h2 = 0; h2 < 2; ++h2) {
    g2l16(gA + h2 * 32 + so0, &As[0][h2][d0]);
    g2l16(gA + h2 * 32 + so1, &As[0][h2][d1]);
    g2l16(gB + h2 * 32 + so0, &Bs[0][h2][d0]);
    g2l16(gB + h2 * 32 + so1, &Bs[0][h2][d1]);
  }
  asm volatile("s_waitcnt vmcnt(0)" ::: "memory");
  __builtin_amdgcn_s_barrier();

  bf16x8 bfr[2][4], af03[2][4], af47[2][4];
  #pragma unroll
  for (int nt = 0; nt < 4; ++nt)
    bfr[0][nt] = *(const bf16x8*)(&Bs[0][0][((wn + nt * 16 + l16) * 4 + sw) * 8]);
  #pragma unroll
  for (int i = 0; i < 4; ++i)
    af03[0][i] = *(const bf16x8*)(&As[0][0][((wm + i * 16 + l16) * 4 + sw) * 8]);

  for (int t = 0; t < 16; ++t) {
    const int c = t & 1, cn = c ^ 1;
    const bool pf = (t < 15);
    const int kn = (t + 1) * 64;

    // ---- S1: issue R3(0) + all 8 g2l; wait R1(0),R2(0); M1(0) ----
    #pragma unroll
    for (int i = 0; i < 4; ++i)
      af47[0][i] = *(const bf16x8*)(&As[c][0][((wm + (4 + i) * 16 + l16) * 4 + sw) * 8]);
    if (pf) {
      #pragma unroll
      for (int h2 = 0; h2 < 2; ++h2) {
        g2l16(gA + kn + h2 * 32 + so0, &As[cn][h2][d0]);
        g2l16(gA + kn + h2 * 32 + so1, &As[cn][h2][d1]);
        g2l16(gB + kn + h2 * 32 + so0, &Bs[cn][h2][d0]);
        g2l16(gB + kn + h2 * 32 + so1, &Bs[cn][h2][d1]);
      }
    }
    asm volatile("s_waitcnt lgkmcnt(4)" ::: "memory");   // R3(0) stays in flight
    __builtin_amdgcn_sched_barrier(0);
    __builtin_amdgcn_s_setprio(1);
    #pragma unroll
    for (int i = 0; i < 4; ++i)
      #pragma unroll
      for (int nt = 0; nt < 4; ++nt)
        acc[i][nt] = __builtin_amdgcn_mfma_f32_16x16x32_bf16(
            af03[0][i], bfr[0][nt], acc[i][nt], 0, 0, 0);
    __builtin_amdgcn_s_setprio(0);

    // ---- S2: issue R1(1),R2(1); wait R3(0) (8 left); M2(0) ----
    #pragma unroll
    for (int nt = 0; nt < 4; ++nt)
      bfr[1][nt] = *(const bf16x8*)(&Bs[c][1][((wn + nt * 16 + l16) * 4 + sw) * 8]);
    #pragma unroll
    for (int i = 0; i < 4; ++i)
      af03[1][i] = *(const bf16x8*)(&As[c][1][((wm + i * 16 + l16) * 4 + sw) * 8]);
    asm volatile("s_waitcnt lgkmcnt(8)" ::: "memory");
    __builtin_amdgcn_sched_barrier(0);
    __builtin_amdgcn_s_setprio(1);
    #pragma unroll
    for (int i = 0; i < 4; ++i)
      #pragma unroll
      for (int nt = 0; nt < 4; ++nt)
        acc[4 + i][nt] = __builtin_amdgcn_mfma_f32_16x16x32_bf16(
            af47[0][i], bfr[0][nt], acc[4 + i][nt], 0, 0, 0);
    __builtin_amdgcn_s_setprio(0);

    // ---- S3: issue R3(1); wait R1(1),R2(1) (4 left); M1(1) ----
    #pragma unroll
    for (int i = 0; i < 4; ++i)
      af47[1][i] = *(const bf16x8*)(&As[c][1][((wm + (4 + i) * 16 + l16) * 4 + sw) * 8]);
    asm volatile("s_waitcnt lgkmcnt(4)" ::: "memory");
    __builtin_amdgcn_sched_barrier(0);
    __builtin_amdgcn_s_setprio(1);
    #pragma unroll
    for (int i = 0; i < 4; ++i)
      #pragma unroll
      for (int nt = 0; nt < 4; ++nt)
        acc[i][nt] = __builtin_amdgcn_mfma_f32_16x16x32_bf16(
            af03[1][i], bfr[1][nt], acc[i][nt], 0, 0, 0);
    __builtin_amdgcn_s_setprio(0);

    // ---- S4: wait R3(1); M2(1); vmcnt(0)+barrier; issue next R1(0),R2(0) ----
    asm volatile("s_waitcnt lgkmcnt(0)" ::: "memory");
    __builtin_amdgcn_sched_barrier(0);
    __builtin_amdgcn_s_setprio(1);
    #pragma unroll
    for (int i = 0; i < 4; ++i)
      #pragma unroll
      for (int nt = 0; nt < 4; ++nt)
        acc[4 + i][nt] = __builtin_amdgcn_mfma_f32_16x16x32_bf16(
            af47[1][i], bfr[1][nt], acc[4 + i][nt], 0, 0, 0);
    __builtin_amdgcn_s_setprio(0);
    if (pf) {
      asm volatile("s_waitcnt vmcnt(0)" ::: "memory");   // ~3 sections after issue
      __builtin_amdgcn_s_barrier();
      #pragma unroll
      for (int nt = 0; nt < 4; ++nt)
        bfr[0][nt] = *(const bf16x8*)(&Bs[cn][0][((wn + nt * 16 + l16) * 4 + sw) * 8]);
      #pragma unroll
      for (int i = 0; i < 4; ++i)
        af03[0][i] = *(const bf16x8*)(&As[cn][0][((wm + i * 16 + l16) * 4 + sw) * 8]);
    }
  }

  if (wsel < 2) {
    const float* bias = (wsel == 0) ? bqv : bkv;
    uint16_t* outp = (wsel == 0) ? qout : kout;
    const float scl = (wsel == 0) ? 0.18033688f : 1.0f;
    #pragma unroll
    for (int nt = 0; nt < 4; ++nt) {
      const int n = n0e + wn + nt * 16 + l16;
      const int h = n >> 6, hd = n & 63;
      const float bia = bias[n];
      #pragma unroll
      for (int mt = 0; mt < 8; ++mt) {
        #pragma unroll
        for (int r = 0; r < 4; ++r) {
          const int m = m0e + wm + mt * 16 + quad * 4 + r;
          const int bb = m >> 11, s = m & (S_ - 1);
          outp[(((size_t)(bb * H_ + h)) * S_ + s) * HD_ + hd] =
              f32_to_bf16((acc[mt][nt][r] + bia) * scl);
        }
      }
    }
  } else {
    #pragma unroll
    for (int mt = 0; mt < 8; ++mt) {
      #pragma unroll
      for (int r = 0; r < 4; ++r) {
        const int m = m0e + wm + mt * 16 + quad * 4 + r;
        const int h = m >> 6, hd = m & 63;
        const float bia = bvv[m];
        #pragma unroll
        for (int nt = 0; nt < 4; ++nt) {
          const int n = n0e + wn + nt * 16 + l16;
          const int bb = n >> 11, s = n & (S_ - 1);
          vtout[(((size_t)(bb * H_ + h)) * HD_ + hd) * S_ + s] =
              f32_to_bf16(acc[mt][nt][r] + bia);
        }
      }
    }
  }
}

// flash v6: double-buffered K/V across key-tiles: issue tile t+1's 4 g2l16
// BEFORE computing tile t, __syncthreads after compute -- the QK/softmax/PV
// chain covers the load latency. setprio(1) around both MFMA clusters.
// LDS 41.2KB -> 3 blocks/CU. (R2: dropped out of top-5; keep as-is.)
__global__ __launch_bounds__(256)
void flash_attn(const uint16_t* __restrict__ qb, const uint16_t* __restrict__ kb,
                const uint16_t* __restrict__ vtb, uint16_t* __restrict__ ao)
{
  __shared__ __align__(16) uint16_t ks[2][2][2048];   // [buf][chunk c][64r x 32c]
  __shared__ __align__(16) uint16_t vs[2][2][2048];   // [buf][chunk c][64hd x 32k]
  __shared__ __align__(16) uint16_t p_lds[4][16][72]; // P transpose, wave-private

  const int bh = blockIdx.x;
  const int qt = (int)(gridDim.y - 1u - blockIdx.y);  // heavy blocks first
  const int wave = threadIdx.x >> 6, lane = threadIdx.x & 63;
  const int quad = lane >> 4, l16 = lane & 15;
  const int sw = quad ^ ((l16 >> 1) & 3);
  const int q0 = qt * 64;

  const uint16_t* Q  = qb  + (size_t)bh * S_ * HD_;
  const uint16_t* Kp = kb  + (size_t)bh * S_ * HD_;
  const uint16_t* Vt = vtb + (size_t)bh * HD_ * S_;

  // Q fragments for this wave's 16 rows: A[m=l16][k=quad*8+j]
  const int qrow = q0 + wave * 16;
  bf16x8 aq0 = *(const bf16x8*)(Q + (size_t)(qrow + l16) * HD_ + quad * 8);
  bf16x8 aq1 = *(const bf16x8*)(Q + (size_t)(qrow + l16) * HD_ + 32 + quad * 8);

  // staging: 16 x 1KB groups per tile; wave w handles groups 4w..4w+3.
  // groups 0-7: K (chunk g>>2, rowblk g&3); 8-15: V^T likewise. Swizzled fill.
  const int srow = lane >> 2;                       // local row 0..15
  const int schk = (lane & 3) ^ ((lane >> 3) & 3);  // swizzled source chunk
  const uint16_t* sb[4]; uint16_t* sd0[4]; uint16_t* sd1[4]; int sstep[4];
  #pragma unroll
  for (int j = 0; j < 4; ++j) {
    const int g = wave * 4 + j;
    if (g < 8) {
      const int c = (g >> 2) & 1, rb = g & 3;
      sd0[j] = &ks[0][c][rb * 512];
      sd1[j] = &ks[1][c][rb * 512];
      sb[j] = Kp + (size_t)(rb * 16 + srow) * HD_ + c * 32 + schk * 8;
      sstep[j] = 64 * HD_;          // advance 64 key-rows per tile
    } else {
      const int gg = g - 8, c = (gg >> 2) & 1, rb = gg & 3;
      sd0[j] = &vs[0][c][rb * 512];
      sd1[j] = &vs[1][c][rb * 512];
      sb[j] = Vt + (size_t)(rb * 16 + srow) * S_ + c * 32 + schk * 8;
      sstep[j] = 64;                // advance 64 key-cols per tile
    }
  }

  float lpart[4];
  f32x4 o[4];
  #pragma unroll
  for (int r = 0; r < 4; ++r) lpart[r] = 0.f;
  #pragma unroll
  for (int t = 0; t < 4; ++t)
    #pragma unroll
    for (int e = 0; e < 4; ++e) o[t][e] = 0.f;

  const int rowid = qrow + quad * 4;    // +r = this lane's score rows

  // prologue: stage tile 0 into buf 0
  #pragma unroll
  for (int j = 0; j < 4; ++j) {
    g2l16(sb[j], sd0[j]);
    sb[j] += sstep[j];
  }
  __syncthreads();

  for (int kt = 0; kt <= qt; ++kt) {
    const int kbase = kt * 64;
    const bool diag = (kt == qt);
    const int cb = kt & 1;

    // prefetch tile kt+1 into the other buffer; latency hides under compute
    if (kt < qt) {
      #pragma unroll
      for (int j = 0; j < 4; ++j) {
        g2l16(sb[j], cb ? sd0[j] : sd1[j]);
        sb[j] += sstep[j];
      }
    }

    bf16x8 kf0[4], kf1[4];
    #pragma unroll
    for (int nt = 0; nt < 4; ++nt) {
      kf0[nt] = *(const bf16x8*)(&ks[cb][0][((nt * 16 + l16) * 4 + sw) * 8]);
      kf1[nt] = *(const bf16x8*)(&ks[cb][1][((nt * 16 + l16) * 4 + sw) * 8]);
    }
    f32x4 sacc[4];
    __builtin_amdgcn_s_setprio(1);
    #pragma unroll
    for (int nt = 0; nt < 4; ++nt) {
      #pragma unroll
      for (int e = 0; e < 4; ++e) sacc[nt][e] = 0.f;
      sacc[nt] = __builtin_amdgcn_mfma_f32_16x16x32_bf16(aq0, kf0[nt], sacc[nt], 0, 0, 0);
      sacc[nt] = __builtin_amdgcn_mfma_f32_16x16x32_bf16(aq1, kf1[nt], sacc[nt], 0, 0, 0);
    }
    __builtin_amdgcn_s_setprio(0);

    bf16x8 vf0[4], vf1[4];
    #pragma unroll
    for (int t = 0; t < 4; ++t) {
      vf0[t] = *(const bf16x8*)(&vs[cb][0][((t * 16 + l16) * 4 + sw) * 8]);
      vf1[t] = *(const bf16x8*)(&vs[cb][1][((t * 16 + l16) * 4 + sw) * 8]);
    }

    // max-free softmax: p = exp2(s) (log2e folded into Q); masked -> 0; RTZ
    #pragma unroll
    for (int nt = 0; nt < 4; ++nt) {
      const int kkc = kbase + nt * 16 + l16;
      #pragma unroll
      for (int r = 0; r < 4; ++r) {
        float p = __builtin_amdgcn_exp2f(sacc[nt][r]);
        if (diag && (kkc > rowid + r)) p = 0.f;
        lpart[r] += p;
        p_lds[wave][quad * 4 + r][nt * 16 + l16] = f32_to_bf16_rtz(p);
      }
    }

    // P: C-layout -> A-layout via wave-private LDS (DS ops in-order per wave)
    bf16x8 ap0 = *(const bf16x8*)(&p_lds[wave][l16][quad * 8]);
    bf16x8 ap1 = *(const bf16x8*)(&p_lds[wave][l16][32 + quad * 8]);
    __builtin_amdgcn_s_setprio(1);
    #pragma unroll
    for (int t = 0; t < 4; ++t) {      // O += P V
      o[t] = __builtin_amdgcn_mfma_f32_16x16x32_bf16(ap0, vf0[t], o[t], 0, 0, 0);
      o[t] = __builtin_amdgcn_mfma_f32_16x16x32_bf16(ap1, vf1[t], o[t], 0, 0, 0);
    }
    __builtin_amdgcn_s_setprio(0);
    __syncthreads();    // prefetch landed + all waves done reading buf cb
  }

  // wave-complete rows: butterfly row-sum, then store
  #pragma unroll
  for (int r = 0; r < 4; ++r) {
    lpart[r] += __shfl_xor(lpart[r], 1, 64);
    lpart[r] += __shfl_xor(lpart[r], 2, 64);
    lpart[r] += __shfl_xor(lpart[r], 4, 64);
    lpart[r] += __shfl_xor(lpart[r], 8, 64);
  }
  const int bb = bh >> 4, h = bh & 15;
  #pragma unroll
  for (int t = 0; t < 4; ++t) {
    #pragma unroll
    for (int r = 0; r < 4; ++r) {
      const float ov = o[t][r] / lpart[r];
      ao[((size_t)(bb * S_ + rowid + r)) * D_ + h * HD_ + t * 16 + l16] =
          f32_to_bf16(ov);
    }
  }
}

// out_gemm v3: 64x128 tile, BK=64, double-buffered LDS (48KB) with the
// flash-v6 prefetch pattern that worked: issue next tile's 6 g2l BEFORE
// compute, one __syncthreads per tile (drain happens after compute covers
// the latency).
__global__ __launch_bounds__(256)
void out_gemm(const uint16_t* __restrict__ ab, const uint16_t* __restrict__ wfb,
              const float* __restrict__ bfv, float* __restrict__ out)
{
  __shared__ __align__(16) uint16_t As[2][2][2048];   // [buf][khalf][64x32]
  __shared__ __align__(16) uint16_t Bs[2][2][4096];   // [buf][khalf][128x32]
  const int m0 = blockIdx.y * 64;            // y = m-tile (XCD: id mod 8 = x)
  const int n0 = blockIdx.x * 128;           // x = weight N-tile
  const int lane = threadIdx.x & 63, wave = threadIdx.x >> 6;
  const int quad = lane >> 4, l16 = lane & 15;
  const int wm = (wave >> 1) * 32, wn = (wave & 1) * 64;
  const int sw = quad ^ ((l16 >> 1) & 3);

  f32x4 acc[2][4];
  #pragma unroll
  for (int i = 0; i < 2; ++i)
    #pragma unroll
    for (int j = 0; j < 4; ++j)
      #pragma unroll
      for (int e = 0; e < 4; ++e)
        acc[i][j][e] = 0.f;

  const int sA  = wave * 64 + lane;          // A: 64 rows = 256 slots/panel
  const int sB1 = sA + 256;                  // B: 128 rows = 512 slots/panel
  const int soA = swz_src(sA), soB1 = swz_src(sB1);
  const int dA  = (wave * 64) * 8;
  const int dB1 = (256 + wave * 64) * 8;
  const uint16_t* gA  = ab  + (size_t)m0 * D_ + soA;
  const uint16_t* gB0 = wfb + (size_t)n0 * D_ + soA;
  const uint16_t* gB1 = wfb + (size_t)n0 * D_ + soB1;

  // prologue: tile 0 -> buf 0
  g2l16(gA,       &As[0][0][dA]);
  g2l16(gA  + 32, &As[0][1][dA]);
  g2l16(gB0,      &Bs[0][0][dA]);
  g2l16(gB0 + 32, &Bs[0][1][dA]);
  g2l16(gB1,      &Bs[0][0][dB1]);
  g2l16(gB1 + 32, &Bs[0][1][dB1]);
  __syncthreads();

  for (int t = 0; t < 16; ++t) {
    const int cb = t & 1, cn = cb ^ 1;
    if (t < 15) {
      const int kn = (t + 1) * 64;
      g2l16(gA  + kn,      &As[cn][0][dA]);
      g2l16(gA  + kn + 32, &As[cn][1][dA]);
      g2l16(gB0 + kn,      &Bs[cn][0][dA]);
      g2l16(gB0 + kn + 32, &Bs[cn][1][dA]);
      g2l16(gB1 + kn,      &Bs[cn][0][dB1]);
      g2l16(gB1 + kn + 32, &Bs[cn][1][dB1]);
    }
    bf16x8 af0[2], af1[2], bf0[4], bf1[4];
    #pragma unroll
    for (int mt = 0; mt < 2; ++mt) {
      const int ro = ((wm + mt * 16 + l16) * 4 + sw) * 8;
      af0[mt] = *(const bf16x8*)(&As[cb][0][ro]);
      af1[mt] = *(const bf16x8*)(&As[cb][1][ro]);
    }
    #pragma unroll
    for (int nt = 0; nt < 4; ++nt) {
      const int ro = ((wn + nt * 16 + l16) * 4 + sw) * 8;
      bf0[nt] = *(const bf16x8*)(&Bs[cb][0][ro]);
      bf1[nt] = *(const bf16x8*)(&Bs[cb][1][ro]);
    }
    __builtin_amdgcn_s_setprio(1);
    #pragma unroll
    for (int mt = 0; mt < 2; ++mt)
      #pragma unroll
      for (int nt = 0; nt < 4; ++nt) {
        acc[mt][nt] = __builtin_amdgcn_mfma_f32_16x16x32_bf16(
            af0[mt], bf0[nt], acc[mt][nt], 0, 0, 0);
        acc[mt][nt] = __builtin_amdgcn_mfma_f32_16x16x32_bf16(
            af1[mt], bf1[nt], acc[mt][nt], 0, 0, 0);
      }
    __builtin_amdgcn_s_setprio(0);
    __syncthreads();
  }

  #pragma unroll
  for (int nt = 0; nt < 4; ++nt) {
    const int n = n0 + wn + nt * 16 + l16;
    const float bia = bfv[n];
    #pragma unroll
    for (int mt = 0; mt < 2; ++mt) {
      #pragma unroll
      for (int r = 0; r < 4; ++r) {
        const int m = m0 + wm + mt * 16 + quad * 4 + r;
        out[(size_t)m * D_ + n] = acc[mt][nt][r] + bia;
      }
    }
  }
}

extern "C" void kernel_launch(void* const* d_in, const int* in_sizes, int n_in,
                              void* d_out, int out_size, void* d_ws, size_t ws_size,
                              hipStream_t stream) {
  (void)in_sizes; (void)n_in; (void)out_size; (void)ws_size;
  const float* x  = (const float*)d_in[0];
  const float* Wq = (const float*)d_in[1];
  const float* bq = (const float*)d_in[2];
  const float* Wk = (const float*)d_in[3];
  const float* bk = (const float*)d_in[4];
  const float* Wv = (const float*)d_in[5];
  const float* bv = (const float*)d_in[6];
  const float* Wf = (const float*)d_in[7];
  const float* bf = (const float*)d_in[8];
  float* out = (float*)d_out;

  uint16_t* ws = (uint16_t*)d_ws;
  uint16_t* xb   = ws;
  uint16_t* wqb  = xb  + (size_t)M_ * D_;
  uint16_t* wkb  = wqb + (size_t)D_ * D_;
  uint16_t* wvb  = wkb + (size_t)D_ * D_;
  uint16_t* wfb  = wvb + (size_t)D_ * D_;
  uint16_t* qbuf = wfb + (size_t)D_ * D_;
  uint16_t* kbuf = qbuf + (size_t)M_ * D_;
  uint16_t* vtb  = kbuf + (size_t)M_ * D_;
  uint16_t* aob  = vtb  + (size_t)M_ * D_;

  const int CAST_BLOCKS = (M_ * D_ / 4 + 4 * (D_ * D_ / 4)) / 256;   // 8192
  cast_all<<<CAST_BLOCKS, 256, 0, stream>>>(x, Wq, Wk, Wv, Wf,
                                            xb, wqb, wkb, wvb, wfb);

  qkv_gemm<<<dim3(12, 16), 512, 0, stream>>>(xb, wqb, wkb, wvb, bq, bk, bv,
                                             qbuf, kbuf, vtb);
  flash_attn<<<dim3(32, 32), 256, 0, stream>>>(qbuf, kbuf, vtb, aob);
  out_gemm<<<dim3(8, 64), 256, 0, stream>>>(aob, wfb, bf, out);
}